// Round 11
// baseline (105.449 us; speedup 1.0000x reference)
//
#include <hip/hip_runtime.h>
#include <math.h>

#define LRELU_ALPHA 0.2f
#define NEG_MASK_V -9000000000000000.0f

typedef __attribute__((ext_vector_type(8))) short short8;
typedef __attribute__((ext_vector_type(4))) float floatx4;
typedef __attribute__((ext_vector_type(8))) unsigned short u16x8;
typedef __attribute__((ext_vector_type(4))) unsigned short u16x4;

__device__ __forceinline__ unsigned short f2bf(float x) {
  union { float f; unsigned u; } v; v.f = x;
  unsigned r = v.u + 0x7fff + ((v.u >> 16) & 1);   // RNE
  return (unsigned short)(r >> 16);
}

// ---------------------------------------------------------------------------
// Prep: block 0: u1 = W^T a1, u2 = W^T a2, c1 = b.a1, c2 = b.a2
//       blocks 1..32: Wb = bf16(W)
// ---------------------------------------------------------------------------
__global__ __launch_bounds__(256) void prep_kernel(
    const float* __restrict__ W, const float* __restrict__ b,
    const float* __restrict__ a, unsigned short* __restrict__ Wb,
    float* __restrict__ u1, float* __restrict__ u2, float* __restrict__ cst)
{
  const int t = threadIdx.x;
  if (blockIdx.x == 0) {
    float a1s = 0.f, a2s = 0.f;
    for (int o = 0; o < 256; ++o) {
      const float w = W[o * 256 + t];
      a1s = fmaf(w, a[o], a1s);
      a2s = fmaf(w, a[256 + o], a2s);
    }
    u1[t] = a1s; u2[t] = a2s;
    if (t < 64) {
      float p1 = 0.f, p2 = 0.f;
      #pragma unroll
      for (int q = 0; q < 4; ++q) {
        const float bv = b[t + q * 64];
        p1 = fmaf(bv, a[t + q * 64], p1);
        p2 = fmaf(bv, a[256 + t + q * 64], p2);
      }
      #pragma unroll
      for (int off = 32; off > 0; off >>= 1) {
        p1 += __shfl_xor(p1, off); p2 += __shfl_xor(p2, off);
      }
      if (t == 0) { cst[0] = p1; cst[1] = p2; }
    }
  } else {
    const int base = (blockIdx.x - 1) * 2048 + t * 8;
    const float4 v0 = *(const float4*)&W[base];
    const float4 v1 = *(const float4*)&W[base + 4];
    u16x8 o;
    o[0] = f2bf(v0.x); o[1] = f2bf(v0.y); o[2] = f2bf(v0.z); o[3] = f2bf(v0.w);
    o[4] = f2bf(v1.x); o[5] = f2bf(v1.y); o[6] = f2bf(v1.z); o[7] = f2bf(v1.w);
    *(u16x8*)&Wb[base] = o;
  }
}

// ---------------------------------------------------------------------------
// sdot: exact f32 logit row-terms: s1[n] = h[n].u1 + c1, s2[n] = h[n].u2 + c2
// ---------------------------------------------------------------------------
__global__ __launch_bounds__(256) void sdot_kernel(
    const float* __restrict__ h, const float* __restrict__ u1,
    const float* __restrict__ u2, const float* __restrict__ cst,
    float* __restrict__ s1, float* __restrict__ s2)
{
  const int t = threadIdx.x, l = t & 63, w = t >> 6;
  const long row0 = (long)blockIdx.x * 64 + w * 16;
  const float4 u1v = *(const float4*)&u1[l * 4];
  const float4 u2v = *(const float4*)&u2[l * 4];
  const float c1 = cst[0], c2 = cst[1];
  #pragma unroll
  for (int r = 0; r < 16; ++r) {
    const float4 hv = *(const float4*)&h[(row0 + r) * 256 + l * 4];
    float d1 = hv.x * u1v.x + hv.y * u1v.y + hv.z * u1v.z + hv.w * u1v.w;
    float d2 = hv.x * u2v.x + hv.y * u2v.y + hv.z * u2v.z + hv.w * u2v.w;
    #pragma unroll
    for (int off = 32; off > 0; off >>= 1) {
      d1 += __shfl_xor(d1, off); d2 += __shfl_xor(d2, off);
    }
    if (l == 0) { s1[row0 + r] = d1 + c1; s2[row0 + r] = d2 + c2; }
  }
}

// ---------------------------------------------------------------------------
// zmfma: z = bf16MFMA(h, W) + b, written PRE-FRAGMENTED for attn:
// zf[(bi*8 + kk*4 + lg)*2048 + d*8 + jq]  (u16 units), bi = b*16 + jtile.
// ---------------------------------------------------------------------------
__global__ __launch_bounds__(256) void zmfma_kernel(
    const float* __restrict__ h, const unsigned short* __restrict__ Wb,
    const float* __restrict__ bias, unsigned short* __restrict__ zf)
{
  __shared__ __align__(16) unsigned char smem[46080];
  unsigned short (*h_tile)[72] = (unsigned short(*)[72])smem;            // 9216 B
  unsigned short (*w_tile)[72] = (unsigned short(*)[72])(smem + 9216);   // 36864 B
  unsigned short (*ztile)[68]  = (unsigned short(*)[68])smem;            // 34816 B (epilogue alias)

  const int t = threadIdx.x, l = t & 63, w = t >> 6;
  const int bi = blockIdx.x;
  const long row0 = (long)bi * 64;

  floatx4 acc[4][4];
  #pragma unroll
  for (int mf = 0; mf < 4; ++mf)
    #pragma unroll
    for (int nf = 0; nf < 4; ++nf) acc[mf][nf] = (floatx4)0.f;

  for (int k0 = 0; k0 < 256; k0 += 64) {
    __syncthreads();
    #pragma unroll
    for (int p = 0; p < 4; ++p) {
      const int row = p * 16 + (t >> 4);
      const float4 hv = *(const float4*)&h[(row0 + row) * 256 + k0 + (t & 15) * 4];
      u16x4 hb;
      hb[0] = f2bf(hv.x); hb[1] = f2bf(hv.y); hb[2] = f2bf(hv.z); hb[3] = f2bf(hv.w);
      *(u16x4*)&h_tile[row][(t & 15) * 4] = hb;
    }
    #pragma unroll
    for (int p = 0; p < 8; ++p) {
      const int o = p * 32 + (t >> 3);
      const u16x8 wv = *(const u16x8*)&Wb[o * 256 + k0 + (t & 7) * 8];
      *(u16x8*)&w_tile[o][(t & 7) * 8] = wv;
    }
    __syncthreads();

    #pragma unroll
    for (int kk = 0; kk < 2; ++kk) {
      short8 af[4];
      #pragma unroll
      for (int mf = 0; mf < 4; ++mf)
        af[mf] = *(const short8*)&h_tile[mf * 16 + (l & 15)][kk * 32 + (l >> 4) * 8];
      #pragma unroll
      for (int nf = 0; nf < 4; ++nf) {
        const short8 bf = *(const short8*)&w_tile[w * 64 + nf * 16 + (l & 15)][kk * 32 + (l >> 4) * 8];
        #pragma unroll
        for (int mf = 0; mf < 4; ++mf)
          acc[mf][nf] = __builtin_amdgcn_mfma_f32_16x16x32_bf16(af[mf], bf, acc[mf][nf], 0, 0, 0);
      }
    }
  }

  __syncthreads();   // done reading h/w tiles; reuse as ztile[o][j]
  #pragma unroll
  for (int nf = 0; nf < 4; ++nf) {
    const int o = w * 64 + nf * 16 + (l & 15);
    const float bv = bias[o];
    #pragma unroll
    for (int mf = 0; mf < 4; ++mf) {
      u16x4 zv;
      #pragma unroll
      for (int rg = 0; rg < 4; ++rg) zv[rg] = f2bf(acc[mf][nf][rg] + bv);
      *(u16x4*)&ztile[o][mf * 16 + (l >> 4) * 4] = zv;
    }
  }
  __syncthreads();
  // seg = kk*4+lg; ztile[t][seg*8..+8] -> zf[(bi*8+seg)*2048 + t*8]
  #pragma unroll
  for (int seg = 0; seg < 8; ++seg)
    *(u16x8*)&zf[((size_t)bi * 8 + seg) * 2048 + t * 8] =
        *(const u16x8*)&ztile[t][seg * 8];
}

// ---------------------------------------------------------------------------
// attn: flash attention over graph mask, bf16 MFMA PV.  [R4 config, best
// measured: fixed softmax max (m=0), depth-1 prefetch, 2 syncthreads/phase.]
// grid = 512 (XCD-swizzled); block = 512 thr (8 waves); 64 i-rows/block.
// ---------------------------------------------------------------------------
__global__ __launch_bounds__(512, 4) void attn_kernel(
    const unsigned short* __restrict__ zf, const float* __restrict__ s1g,
    const float* __restrict__ s2g, const int* __restrict__ adj,
    float* __restrict__ out)
{
  __shared__ unsigned short p_lds[64][72];   // 9216 B
  __shared__ float s2s[1024];
  __shared__ float s1s[64];
  __shared__ float sum_lds[64];

  const int t = threadIdx.x;
  const int l = t & 63;
  const int w = t >> 6;

  // XCD-aware bijective swizzle: 512 wgs = 8 xcds * 64
  const int wg = blockIdx.x;
  const int sw = (wg & 7) * 64 + (wg >> 3);
  const int b = sw >> 4;
  const int i0 = (sw & 15) * 64;

  const int i_loc = t >> 3;            // 0..63
  const int jb = (t & 7) * 8;          // 0..56

  const size_t adj_base = (size_t)b * 1024 * 1024 + (size_t)(i0 + i_loc) * 1024 + jb;
  const size_t zf_batch = (size_t)b * 16 * 16384;
  const size_t zf_lane  = (size_t)(l >> 4) * 2048 + (size_t)(w * 32 + (l & 15)) * 8;

  if (t < 64) s1s[t] = s1g[b * 1024 + i0 + t];
  s2s[t] = s2g[b * 1024 + t];
  s2s[512 + t] = s2g[b * 1024 + 512 + t];

  floatx4 acc[4][2];
  #pragma unroll
  for (int mf = 0; mf < 4; ++mf) {
    acc[mf][0] = (floatx4)0.f;
    acc[mf][1] = (floatx4)0.f;
  }
  float sm = 0.f;

  int4 ac0 = *(const int4*)&adj[adj_base];
  int4 ac1 = *(const int4*)&adj[adj_base + 4];

  short8 vz[2][4];
  {
    const unsigned short* zp = zf + zf_batch + zf_lane;
    vz[0][0] = *(const short8*)(zp);
    vz[0][1] = *(const short8*)(zp + 128);
    vz[0][2] = *(const short8*)(zp + 8192);
    vz[0][3] = *(const short8*)(zp + 8320);
  }
  __syncthreads();   // s1s/s2s ready
  const float s1v = s1s[i_loc];

  for (int jt2 = 0; jt2 < 1024; jt2 += 128) {
    #pragma unroll
    for (int ph = 0; ph < 2; ++ph) {
      const int jt = jt2 + ph * 64;

      // ---- masked logits (8/thread), fixed max = 0 ----
      const float4 s2a = *(const float4*)&s2s[jt + jb];
      const float4 s2b = *(const float4*)&s2s[jt + jb + 4];
      float e[8] = {s2a.x, s2a.y, s2a.z, s2a.w, s2b.x, s2b.y, s2b.z, s2b.w};
      const int am[8] = {ac0.x, ac0.y, ac0.z, ac0.w, ac1.x, ac1.y, ac1.z, ac1.w};
      #pragma unroll
      for (int q = 0; q < 8; ++q) {
        float x = s1v + e[q];
        x = fmaxf(x, LRELU_ALPHA * x);       // leaky-relu (alpha < 1)
        e[q] = am[q] > 0 ? x : NEG_MASK_V;
      }

      // ---- prefetch next phase's adj + z fragments ----
      if (jt + 64 < 1024) {
        ac0 = *(const int4*)&adj[adj_base + jt + 64];
        ac1 = *(const int4*)&adj[adj_base + jt + 68];
        const unsigned short* zp =
            zf + zf_batch + (size_t)((jt >> 6) + 1) * 16384 + zf_lane;
        vz[ph ^ 1][0] = *(const short8*)(zp);
        vz[ph ^ 1][1] = *(const short8*)(zp + 128);
        vz[ph ^ 1][2] = *(const short8*)(zp + 8192);
        vz[ph ^ 1][3] = *(const short8*)(zp + 8320);
      }

      // ---- exp + partial sum + bf16 pack ----
      u16x8 pk;
      float p[8];
      #pragma unroll
      for (int q = 0; q < 8; ++q) {
        p[q] = __expf(e[q]);
        sm += p[q];
        pk[q] = f2bf(p[q]);
      }

      __syncthreads();                       // prev MFMA done reading p_lds
      *(u16x8*)&p_lds[i_loc][jb] = pk;
      __syncthreads();                       // p ready

      // ---- PV MFMA: 16 per wave per phase ----
      #pragma unroll
      for (int kk = 0; kk < 2; ++kk) {
        #pragma unroll
        for (int mf = 0; mf < 4; ++mf) {
          const short8 af =
              *(const short8*)&p_lds[mf * 16 + (l & 15)][kk * 32 + (l >> 4) * 8];
          acc[mf][0] = __builtin_amdgcn_mfma_f32_16x16x32_bf16(
              af, vz[ph][kk * 2 + 0], acc[mf][0], 0, 0, 0);
          acc[mf][1] = __builtin_amdgcn_mfma_f32_16x16x32_bf16(
              af, vz[ph][kk * 2 + 1], acc[mf][1], 0, 0, 0);
        }
      }
    }
  }

  // ---- final row-sum reduce (8 threads/row, lane-adjacent) ----
  sm += __shfl_xor(sm, 1);
  sm += __shfl_xor(sm, 2);
  sm += __shfl_xor(sm, 4);
  if ((t & 7) == 0) sum_lds[i_loc] = sm;
  __syncthreads();

  const size_t obase = ((size_t)b * 1024 + i0) * 256 + w * 32;
  #pragma unroll
  for (int mf = 0; mf < 4; ++mf) {
    const int rbase = mf * 16 + ((l >> 4) << 2);
    #pragma unroll
    for (int rg = 0; rg < 4; ++rg) {
      const float inv = 1.0f / sum_lds[rbase + rg];
      #pragma unroll
      for (int nf = 0; nf < 2; ++nf) {
        float v = acc[mf][nf][rg] * inv;
        v = v > 0.f ? v : expm1f(v);
        out[obase + (size_t)(rbase + rg) * 256 + nf * 16 + (l & 15)] = v;
      }
    }
  }
}

// ---------------------------------------------------------------------------
// MEASUREMENT ROUND: attn launched TWICE (deterministic, identical output).
// attn_dur = total(this round) - total(R4 base). All kernels R4-identical.
// ---------------------------------------------------------------------------
extern "C" void kernel_launch(void* const* d_in, const int* in_sizes, int n_in,
                              void* d_out, int out_size, void* d_ws, size_t ws_size,
                              hipStream_t stream) {
  const float* h    = (const float*)d_in[0];   // [32,1024,256] f32
  const int*   adj  = (const int*)d_in[1];     // [32,1024,1024] i32
  const float* W    = (const float*)d_in[2];   // [256,256] f32
  const float* bias = (const float*)d_in[3];   // [256] f32
  const float* a    = (const float*)d_in[4];   // [512] f32
  float* out = (float*)d_out;                  // [32,1024,256] f32

  // workspace layout
  unsigned short* zf = (unsigned short*)d_ws;                       // 16 MB
  float* s1  = (float*)((char*)d_ws + 16777216);                    // 128 KB
  float* s2  = (float*)((char*)d_ws + 16908288);                    // 128 KB
  float* u1  = (float*)((char*)d_ws + 17039360);                    // 1 KB
  float* u2  = (float*)((char*)d_ws + 17040384);                    // 1 KB
  float* cst = (float*)((char*)d_ws + 17041408);                    // 8 B
  unsigned short* Wb = (unsigned short*)((char*)d_ws + 17825792);   // 128 KB

  prep_kernel<<<dim3(33), dim3(256), 0, stream>>>(W, bias, a, Wb, u1, u2, cst);
  sdot_kernel<<<dim3(512), dim3(256), 0, stream>>>(h, u1, u2, cst, s1, s2);
  zmfma_kernel<<<dim3(512), dim3(256), 0, stream>>>(h, Wb, bias, zf);
  attn_kernel<<<dim3(512), dim3(512), 0, stream>>>(zf, s1, s2, adj, out);
  attn_kernel<<<dim3(512), dim3(512), 0, stream>>>(zf, s1, s2, adj, out);
}

// Round 12
// 69.521 us; speedup vs baseline: 1.5168x; 1.5168x over previous
//
#include <hip/hip_runtime.h>
#include <math.h>

#define LRELU_ALPHA 0.2f
#define NEG_MASK_V -9000000000000000.0f

typedef __attribute__((ext_vector_type(8))) short short8;
typedef __attribute__((ext_vector_type(4))) float floatx4;
typedef __attribute__((ext_vector_type(8))) unsigned short u16x8;
typedef __attribute__((ext_vector_type(4))) unsigned short u16x4;

__device__ __forceinline__ unsigned short f2bf(float x) {
  union { float f; unsigned u; } v; v.f = x;
  unsigned r = v.u + 0x7fff + ((v.u >> 16) & 1);   // RNE
  return (unsigned short)(r >> 16);
}

// hw packed f32->bf16 (RNE)
__device__ __forceinline__ unsigned cvt_pk_bf16(float lo, float hi) {
  unsigned r;
  asm("v_cvt_pk_bf16_f32 %0, %1, %2" : "=v"(r) : "v"(lo), "v"(hi));
  return r;
}

// ---------------------------------------------------------------------------
// Prep: block 0: u1 = W^T a1, u2 = W^T a2, c1 = b.a1, c2 = b.a2
//       blocks 1..32: Wf = bf16(W) PRE-FRAGMENTED:
//       Wf[(region*256 + o)*8 + q], region = k>>3, so a 16-lane fragment
//       read is 256 B contiguous.
// ---------------------------------------------------------------------------
__global__ __launch_bounds__(256) void prep_kernel(
    const float* __restrict__ W, const float* __restrict__ b,
    const float* __restrict__ a, unsigned short* __restrict__ Wf,
    float* __restrict__ u1, float* __restrict__ u2, float* __restrict__ cst)
{
  const int t = threadIdx.x;
  if (blockIdx.x == 0) {
    float a1s = 0.f, a2s = 0.f;
    #pragma unroll 4
    for (int o = 0; o < 256; ++o) {
      const float w = W[o * 256 + t];
      a1s = fmaf(w, a[o], a1s);
      a2s = fmaf(w, a[256 + o], a2s);
    }
    u1[t] = a1s; u2[t] = a2s;
    if (t < 64) {
      float p1 = 0.f, p2 = 0.f;
      #pragma unroll
      for (int q = 0; q < 4; ++q) {
        const float bv = b[t + q * 64];
        p1 = fmaf(bv, a[t + q * 64], p1);
        p2 = fmaf(bv, a[256 + t + q * 64], p2);
      }
      #pragma unroll
      for (int off = 32; off > 0; off >>= 1) {
        p1 += __shfl_xor(p1, off); p2 += __shfl_xor(p2, off);
      }
      if (t == 0) { cst[0] = p1; cst[1] = p2; }
    }
  } else {
    const int base = (blockIdx.x - 1) * 2048 + t * 8;   // flat f32 idx into W
    const int o = base >> 8;                            // W row
    const int k = base & 255;                           // col start (mult of 8)
    const int region = k >> 3;
    const float4 v0 = *(const float4*)&W[base];
    const float4 v1 = *(const float4*)&W[base + 4];
    u16x8 ov;
    ov[0] = f2bf(v0.x); ov[1] = f2bf(v0.y); ov[2] = f2bf(v0.z); ov[3] = f2bf(v0.w);
    ov[4] = f2bf(v1.x); ov[5] = f2bf(v1.y); ov[6] = f2bf(v1.z); ov[7] = f2bf(v1.w);
    *(u16x8*)&Wf[((size_t)region * 256 + o) * 8] = ov;
  }
}

// ---------------------------------------------------------------------------
// zmfma v4 (+fused exact sdot): BM=32 tile, 1024 blocks (4/CU) for TLP.
// z = bf16MFMA(h, W) + b -> zf (pre-fragmented) direct from accumulators;
// s1/s2 computed in exact f32 from the staged h float4s (no second h pass).
// h tile double-buffered in LDS: ONE barrier per k-step.
// ---------------------------------------------------------------------------
__global__ __launch_bounds__(256) void zmfma_kernel(
    const float* __restrict__ h, const unsigned short* __restrict__ Wf,
    const float* __restrict__ bias, const float* __restrict__ u1,
    const float* __restrict__ u2, const float* __restrict__ cst,
    unsigned short* __restrict__ zf, float* __restrict__ s1,
    float* __restrict__ s2)
{
  __shared__ unsigned short h_tile[2][32][72];   // 9216 B

  const int t = threadIdx.x, l = t & 63, w = t >> 6;
  const int g = l >> 4;
  const int bi = blockIdx.x;                      // [0,1024): 32-row tile
  const long row0 = (long)bi * 32;

  floatx4 acc[2][4];
  #pragma unroll
  for (int mf = 0; mf < 2; ++mf)
    #pragma unroll
    for (int nf = 0; nf < 4; ++nf) acc[mf][nf] = (floatx4)0.f;

  float d1a[2] = {0.f, 0.f};
  float d2a[2] = {0.f, 0.f};

  const int srow = t >> 4, scol = (t & 15) * 4;

  // stage h chunk 0 into buf 0 (+ fused s-dot partials)
  {
    const float4 u1v = *(const float4*)&u1[scol];
    const float4 u2v = *(const float4*)&u2[scol];
    #pragma unroll
    for (int p = 0; p < 2; ++p) {
      const float4 hv = *(const float4*)&h[(row0 + p * 16 + srow) * 256 + scol];
      d1a[p] = fmaf(hv.x, u1v.x, fmaf(hv.y, u1v.y, fmaf(hv.z, u1v.z, fmaf(hv.w, u1v.w, d1a[p]))));
      d2a[p] = fmaf(hv.x, u2v.x, fmaf(hv.y, u2v.y, fmaf(hv.z, u2v.z, fmaf(hv.w, u2v.w, d2a[p]))));
      uint2 hb;
      hb.x = cvt_pk_bf16(hv.x, hv.y);
      hb.y = cvt_pk_bf16(hv.z, hv.w);
      *(uint2*)&h_tile[0][p * 16 + srow][scol] = hb;
    }
  }
  __syncthreads();

  #pragma unroll
  for (int s = 0; s < 4; ++s) {
    // issue next h chunk first (writes the other buffer) + fused s-dots
    if (s < 3) {
      const int k0n = (s + 1) * 64;
      const float4 u1v = *(const float4*)&u1[k0n + scol];
      const float4 u2v = *(const float4*)&u2[k0n + scol];
      #pragma unroll
      for (int p = 0; p < 2; ++p) {
        const float4 hv =
            *(const float4*)&h[(row0 + p * 16 + srow) * 256 + k0n + scol];
        d1a[p] = fmaf(hv.x, u1v.x, fmaf(hv.y, u1v.y, fmaf(hv.z, u1v.z, fmaf(hv.w, u1v.w, d1a[p]))));
        d2a[p] = fmaf(hv.x, u2v.x, fmaf(hv.y, u2v.y, fmaf(hv.z, u2v.z, fmaf(hv.w, u2v.w, d2a[p]))));
        uint2 hb;
        hb.x = cvt_pk_bf16(hv.x, hv.y);
        hb.y = cvt_pk_bf16(hv.z, hv.w);
        *(uint2*)&h_tile[(s + 1) & 1][p * 16 + srow][scol] = hb;
      }
    }

    // W fragments from L2 (16 lanes = 256B contiguous)
    short8 wf[2][4];
    #pragma unroll
    for (int kk = 0; kk < 2; ++kk)
      #pragma unroll
      for (int nf = 0; nf < 4; ++nf)
        wf[kk][nf] = *(const short8*)&Wf[
            ((size_t)(s * 8 + kk * 4 + g) * 256 + w * 64 + nf * 16 + (l & 15)) * 8];

    // MFMA on current buffer: 16 per wave per step
    #pragma unroll
    for (int kk = 0; kk < 2; ++kk) {
      short8 af[2];
      #pragma unroll
      for (int mf = 0; mf < 2; ++mf)
        af[mf] = *(const short8*)&h_tile[s & 1][mf * 16 + (l & 15)][kk * 32 + g * 8];
      #pragma unroll
      for (int nf = 0; nf < 4; ++nf) {
        #pragma unroll
        for (int mf = 0; mf < 2; ++mf)
          acc[mf][nf] = __builtin_amdgcn_mfma_f32_16x16x32_bf16(
              af[mf], wf[kk][nf], acc[mf][nf], 0, 0, 0);
      }
    }
    if (s < 3) __syncthreads();
  }

  // fused s1/s2 reduce: 16 threads (t&15) share a row
  {
    const float c1 = cst[0], c2 = cst[1];
    #pragma unroll
    for (int p = 0; p < 2; ++p) {
      float d1 = d1a[p], d2 = d2a[p];
      #pragma unroll
      for (int off = 8; off > 0; off >>= 1) {
        d1 += __shfl_xor(d1, off); d2 += __shfl_xor(d2, off);
      }
      if ((t & 15) == 0) {
        const long row = row0 + p * 16 + srow;
        s1[row] = d1 + c1; s2[row] = d2 + c2;
      }
    }
  }

  // epilogue: zf direct from accumulators.
  // tile-local row jl = mf*16 + g*4 + rg; j_in64 = (bi&1)*32 + jl
  // region = (bi&1)*4 + mf*2 + (g>>1); jq = (g&1)*4 + rg
  #pragma unroll
  for (int nf = 0; nf < 4; ++nf) {
    const int o = w * 64 + nf * 16 + (l & 15);
    const float bv = bias[o];
    #pragma unroll
    for (int mf = 0; mf < 2; ++mf) {
      const int region = (bi & 1) * 4 + mf * 2 + (g >> 1);
      const int jq = (g & 1) * 4;
      uint2 zv;
      zv.x = cvt_pk_bf16(acc[mf][nf][0] + bv, acc[mf][nf][1] + bv);
      zv.y = cvt_pk_bf16(acc[mf][nf][2] + bv, acc[mf][nf][3] + bv);
      *(uint2*)&zf[((size_t)(bi >> 1) * 8 + region) * 2048 + (size_t)o * 8 + jq] = zv;
    }
  }
}

// ---------------------------------------------------------------------------
// attn: flash attention over graph mask, bf16 MFMA PV.  [R4 config, at its
// HBM roofline ~30 us: fixed softmax max (m=0), depth-1 prefetch,
// 2 syncthreads/phase.]  grid = 512 (XCD-swizzled); block = 512 thr.
// ---------------------------------------------------------------------------
__global__ __launch_bounds__(512, 4) void attn_kernel(
    const unsigned short* __restrict__ zf, const float* __restrict__ s1g,
    const float* __restrict__ s2g, const int* __restrict__ adj,
    float* __restrict__ out)
{
  __shared__ unsigned short p_lds[64][72];   // 9216 B
  __shared__ float s2s[1024];
  __shared__ float s1s[64];
  __shared__ float sum_lds[64];

  const int t = threadIdx.x;
  const int l = t & 63;
  const int w = t >> 6;

  // XCD-aware bijective swizzle: 512 wgs = 8 xcds * 64
  const int wg = blockIdx.x;
  const int sw = (wg & 7) * 64 + (wg >> 3);
  const int b = sw >> 4;
  const int i0 = (sw & 15) * 64;

  const int i_loc = t >> 3;            // 0..63
  const int jb = (t & 7) * 8;          // 0..56

  const size_t adj_base = (size_t)b * 1024 * 1024 + (size_t)(i0 + i_loc) * 1024 + jb;
  const size_t zf_batch = (size_t)b * 16 * 16384;
  const size_t zf_lane  = (size_t)(l >> 4) * 2048 + (size_t)(w * 32 + (l & 15)) * 8;

  if (t < 64) s1s[t] = s1g[b * 1024 + i0 + t];
  s2s[t] = s2g[b * 1024 + t];
  s2s[512 + t] = s2g[b * 1024 + 512 + t];

  floatx4 acc[4][2];
  #pragma unroll
  for (int mf = 0; mf < 4; ++mf) {
    acc[mf][0] = (floatx4)0.f;
    acc[mf][1] = (floatx4)0.f;
  }
  float sm = 0.f;

  int4 ac0 = *(const int4*)&adj[adj_base];
  int4 ac1 = *(const int4*)&adj[adj_base + 4];

  short8 vz[2][4];
  {
    const unsigned short* zp = zf + zf_batch + zf_lane;
    vz[0][0] = *(const short8*)(zp);
    vz[0][1] = *(const short8*)(zp + 128);
    vz[0][2] = *(const short8*)(zp + 8192);
    vz[0][3] = *(const short8*)(zp + 8320);
  }
  __syncthreads();   // s1s/s2s ready
  const float s1v = s1s[i_loc];

  for (int jt2 = 0; jt2 < 1024; jt2 += 128) {
    #pragma unroll
    for (int ph = 0; ph < 2; ++ph) {
      const int jt = jt2 + ph * 64;

      // ---- masked logits (8/thread), fixed max = 0 ----
      const float4 s2a = *(const float4*)&s2s[jt + jb];
      const float4 s2b = *(const float4*)&s2s[jt + jb + 4];
      float e[8] = {s2a.x, s2a.y, s2a.z, s2a.w, s2b.x, s2b.y, s2b.z, s2b.w};
      const int am[8] = {ac0.x, ac0.y, ac0.z, ac0.w, ac1.x, ac1.y, ac1.z, ac1.w};
      #pragma unroll
      for (int q = 0; q < 8; ++q) {
        float x = s1v + e[q];
        x = fmaxf(x, LRELU_ALPHA * x);       // leaky-relu (alpha < 1)
        e[q] = am[q] > 0 ? x : NEG_MASK_V;
      }

      // ---- prefetch next phase's adj + z fragments ----
      if (jt + 64 < 1024) {
        ac0 = *(const int4*)&adj[adj_base + jt + 64];
        ac1 = *(const int4*)&adj[adj_base + jt + 68];
        const unsigned short* zp =
            zf + zf_batch + (size_t)((jt >> 6) + 1) * 16384 + zf_lane;
        vz[ph ^ 1][0] = *(const short8*)(zp);
        vz[ph ^ 1][1] = *(const short8*)(zp + 128);
        vz[ph ^ 1][2] = *(const short8*)(zp + 8192);
        vz[ph ^ 1][3] = *(const short8*)(zp + 8320);
      }

      // ---- exp + partial sum + hw bf16 pack ----
      float p[8];
      #pragma unroll
      for (int q = 0; q < 8; ++q) { p[q] = __expf(e[q]); sm += p[q]; }
      uint4 pk;
      pk.x = cvt_pk_bf16(p[0], p[1]);
      pk.y = cvt_pk_bf16(p[2], p[3]);
      pk.z = cvt_pk_bf16(p[4], p[5]);
      pk.w = cvt_pk_bf16(p[6], p[7]);

      __syncthreads();                       // prev MFMA done reading p_lds
      *(uint4*)&p_lds[i_loc][jb] = pk;
      __syncthreads();                       // p ready

      // ---- PV MFMA: 16 per wave per phase ----
      #pragma unroll
      for (int kk = 0; kk < 2; ++kk) {
        #pragma unroll
        for (int mf = 0; mf < 4; ++mf) {
          const short8 af =
              *(const short8*)&p_lds[mf * 16 + (l & 15)][kk * 32 + (l >> 4) * 8];
          acc[mf][0] = __builtin_amdgcn_mfma_f32_16x16x32_bf16(
              af, vz[ph][kk * 2 + 0], acc[mf][0], 0, 0, 0);
          acc[mf][1] = __builtin_amdgcn_mfma_f32_16x16x32_bf16(
              af, vz[ph][kk * 2 + 1], acc[mf][1], 0, 0, 0);
        }
      }
    }
  }

  // ---- final row-sum reduce (8 threads/row, lane-adjacent) ----
  sm += __shfl_xor(sm, 1);
  sm += __shfl_xor(sm, 2);
  sm += __shfl_xor(sm, 4);
  if ((t & 7) == 0) sum_lds[i_loc] = sm;
  __syncthreads();

  const size_t obase = ((size_t)b * 1024 + i0) * 256 + w * 32;
  #pragma unroll
  for (int mf = 0; mf < 4; ++mf) {
    const int rbase = mf * 16 + ((l >> 4) << 2);
    #pragma unroll
    for (int rg = 0; rg < 4; ++rg) {
      const float inv = 1.0f / sum_lds[rbase + rg];
      #pragma unroll
      for (int nf = 0; nf < 2; ++nf) {
        float v = acc[mf][nf][rg] * inv;
        v = v > 0.f ? v : expm1f(v);
        out[obase + (size_t)(rbase + rg) * 256 + nf * 16 + (l & 15)] = v;
      }
    }
  }
}

// ---------------------------------------------------------------------------
extern "C" void kernel_launch(void* const* d_in, const int* in_sizes, int n_in,
                              void* d_out, int out_size, void* d_ws, size_t ws_size,
                              hipStream_t stream) {
  const float* h    = (const float*)d_in[0];   // [32,1024,256] f32
  const int*   adj  = (const int*)d_in[1];     // [32,1024,1024] i32
  const float* W    = (const float*)d_in[2];   // [256,256] f32
  const float* bias = (const float*)d_in[3];   // [256] f32
  const float* a    = (const float*)d_in[4];   // [512] f32
  float* out = (float*)d_out;                  // [32,1024,256] f32

  // workspace layout
  unsigned short* zf = (unsigned short*)d_ws;                       // 16 MB
  float* s1  = (float*)((char*)d_ws + 16777216);                    // 128 KB
  float* s2  = (float*)((char*)d_ws + 16908288);                    // 128 KB
  float* u1  = (float*)((char*)d_ws + 17039360);                    // 1 KB
  float* u2  = (float*)((char*)d_ws + 17040384);                    // 1 KB
  float* cst = (float*)((char*)d_ws + 17041408);                    // 8 B
  unsigned short* Wf = (unsigned short*)((char*)d_ws + 17825792);   // 128 KB

  prep_kernel<<<dim3(33), dim3(256), 0, stream>>>(W, bias, a, Wf, u1, u2, cst);
  zmfma_kernel<<<dim3(1024), dim3(256), 0, stream>>>(h, Wf, bias, u1, u2, cst, zf, s1, s2);
  attn_kernel<<<dim3(512), dim3(512), 0, stream>>>(zf, s1, s2, adj, out);
}

// Round 13
// 68.881 us; speedup vs baseline: 1.5309x; 1.0093x over previous
//
#include <hip/hip_runtime.h>
#include <math.h>

#define LRELU_ALPHA 0.2f
#define NEG_MASK_V -9000000000000000.0f

typedef __attribute__((ext_vector_type(8))) short short8;
typedef __attribute__((ext_vector_type(4))) float floatx4;
typedef __attribute__((ext_vector_type(8))) unsigned short u16x8;
typedef __attribute__((ext_vector_type(4))) unsigned short u16x4;

__device__ __forceinline__ unsigned short f2bf(float x) {
  union { float f; unsigned u; } v; v.f = x;
  unsigned r = v.u + 0x7fff + ((v.u >> 16) & 1);   // RNE
  return (unsigned short)(r >> 16);
}

// hw packed f32->bf16 (RNE)
__device__ __forceinline__ unsigned cvt_pk_bf16(float lo, float hi) {
  unsigned r;
  asm("v_cvt_pk_bf16_f32 %0, %1, %2" : "=v"(r) : "v"(lo), "v"(hi));
  return r;
}

// ---------------------------------------------------------------------------
// Prep: block 0: u1 = W^T a1, u2 = W^T a2, c1 = b.a1, c2 = b.a2
//       blocks 1..32: Wf = bf16(W) PRE-FRAGMENTED:
//       Wf[(region*256 + o)*8 + q], region = k>>3, so a 16-lane fragment
//       read is 256 B contiguous.
// ---------------------------------------------------------------------------
__global__ __launch_bounds__(256) void prep_kernel(
    const float* __restrict__ W, const float* __restrict__ b,
    const float* __restrict__ a, unsigned short* __restrict__ Wf,
    float* __restrict__ u1, float* __restrict__ u2, float* __restrict__ cst)
{
  const int t = threadIdx.x;
  if (blockIdx.x == 0) {
    float a1s = 0.f, a2s = 0.f;
    #pragma unroll 4
    for (int o = 0; o < 256; ++o) {
      const float w = W[o * 256 + t];
      a1s = fmaf(w, a[o], a1s);
      a2s = fmaf(w, a[256 + o], a2s);
    }
    u1[t] = a1s; u2[t] = a2s;
    if (t < 64) {
      float p1 = 0.f, p2 = 0.f;
      #pragma unroll
      for (int q = 0; q < 4; ++q) {
        const float bv = b[t + q * 64];
        p1 = fmaf(bv, a[t + q * 64], p1);
        p2 = fmaf(bv, a[256 + t + q * 64], p2);
      }
      #pragma unroll
      for (int off = 32; off > 0; off >>= 1) {
        p1 += __shfl_xor(p1, off); p2 += __shfl_xor(p2, off);
      }
      if (t == 0) { cst[0] = p1; cst[1] = p2; }
    }
  } else {
    const int base = (blockIdx.x - 1) * 2048 + t * 8;   // flat f32 idx into W
    const int o = base >> 8;                            // W row
    const int k = base & 255;                           // col start (mult of 8)
    const int region = k >> 3;
    const float4 v0 = *(const float4*)&W[base];
    const float4 v1 = *(const float4*)&W[base + 4];
    u16x8 ov;
    ov[0] = f2bf(v0.x); ov[1] = f2bf(v0.y); ov[2] = f2bf(v0.z); ov[3] = f2bf(v0.w);
    ov[4] = f2bf(v1.x); ov[5] = f2bf(v1.y); ov[6] = f2bf(v1.z); ov[7] = f2bf(v1.w);
    *(u16x8*)&Wf[((size_t)region * 256 + o) * 8] = ov;
  }
}

// ---------------------------------------------------------------------------
// zmfma v4 (+fused exact sdot): BM=32 tile, 1024 blocks (4/CU) for TLP.
// z = bf16MFMA(h, W) + b -> zf (pre-fragmented) direct from accumulators;
// s1/s2 computed in exact f32 from the staged h float4s (no second h pass).
// h tile double-buffered in LDS: ONE barrier per k-step.  [R12, unchanged]
// ---------------------------------------------------------------------------
__global__ __launch_bounds__(256) void zmfma_kernel(
    const float* __restrict__ h, const unsigned short* __restrict__ Wf,
    const float* __restrict__ bias, const float* __restrict__ u1,
    const float* __restrict__ u2, const float* __restrict__ cst,
    unsigned short* __restrict__ zf, float* __restrict__ s1,
    float* __restrict__ s2)
{
  __shared__ unsigned short h_tile[2][32][72];   // 9216 B

  const int t = threadIdx.x, l = t & 63, w = t >> 6;
  const int g = l >> 4;
  const int bi = blockIdx.x;                      // [0,1024): 32-row tile
  const long row0 = (long)bi * 32;

  floatx4 acc[2][4];
  #pragma unroll
  for (int mf = 0; mf < 2; ++mf)
    #pragma unroll
    for (int nf = 0; nf < 4; ++nf) acc[mf][nf] = (floatx4)0.f;

  float d1a[2] = {0.f, 0.f};
  float d2a[2] = {0.f, 0.f};

  const int srow = t >> 4, scol = (t & 15) * 4;

  // stage h chunk 0 into buf 0 (+ fused s-dot partials)
  {
    const float4 u1v = *(const float4*)&u1[scol];
    const float4 u2v = *(const float4*)&u2[scol];
    #pragma unroll
    for (int p = 0; p < 2; ++p) {
      const float4 hv = *(const float4*)&h[(row0 + p * 16 + srow) * 256 + scol];
      d1a[p] = fmaf(hv.x, u1v.x, fmaf(hv.y, u1v.y, fmaf(hv.z, u1v.z, fmaf(hv.w, u1v.w, d1a[p]))));
      d2a[p] = fmaf(hv.x, u2v.x, fmaf(hv.y, u2v.y, fmaf(hv.z, u2v.z, fmaf(hv.w, u2v.w, d2a[p]))));
      uint2 hb;
      hb.x = cvt_pk_bf16(hv.x, hv.y);
      hb.y = cvt_pk_bf16(hv.z, hv.w);
      *(uint2*)&h_tile[0][p * 16 + srow][scol] = hb;
    }
  }
  __syncthreads();

  #pragma unroll
  for (int s = 0; s < 4; ++s) {
    // issue next h chunk first (writes the other buffer) + fused s-dots
    if (s < 3) {
      const int k0n = (s + 1) * 64;
      const float4 u1v = *(const float4*)&u1[k0n + scol];
      const float4 u2v = *(const float4*)&u2[k0n + scol];
      #pragma unroll
      for (int p = 0; p < 2; ++p) {
        const float4 hv =
            *(const float4*)&h[(row0 + p * 16 + srow) * 256 + k0n + scol];
        d1a[p] = fmaf(hv.x, u1v.x, fmaf(hv.y, u1v.y, fmaf(hv.z, u1v.z, fmaf(hv.w, u1v.w, d1a[p]))));
        d2a[p] = fmaf(hv.x, u2v.x, fmaf(hv.y, u2v.y, fmaf(hv.z, u2v.z, fmaf(hv.w, u2v.w, d2a[p]))));
        uint2 hb;
        hb.x = cvt_pk_bf16(hv.x, hv.y);
        hb.y = cvt_pk_bf16(hv.z, hv.w);
        *(uint2*)&h_tile[(s + 1) & 1][p * 16 + srow][scol] = hb;
      }
    }

    // W fragments from L2 (16 lanes = 256B contiguous)
    short8 wf[2][4];
    #pragma unroll
    for (int kk = 0; kk < 2; ++kk)
      #pragma unroll
      for (int nf = 0; nf < 4; ++nf)
        wf[kk][nf] = *(const short8*)&Wf[
            ((size_t)(s * 8 + kk * 4 + g) * 256 + w * 64 + nf * 16 + (l & 15)) * 8];

    // MFMA on current buffer: 16 per wave per step
    #pragma unroll
    for (int kk = 0; kk < 2; ++kk) {
      short8 af[2];
      #pragma unroll
      for (int mf = 0; mf < 2; ++mf)
        af[mf] = *(const short8*)&h_tile[s & 1][mf * 16 + (l & 15)][kk * 32 + g * 8];
      #pragma unroll
      for (int nf = 0; nf < 4; ++nf) {
        #pragma unroll
        for (int mf = 0; mf < 2; ++mf)
          acc[mf][nf] = __builtin_amdgcn_mfma_f32_16x16x32_bf16(
              af[mf], wf[kk][nf], acc[mf][nf], 0, 0, 0);
      }
    }
    if (s < 3) __syncthreads();
  }

  // fused s1/s2 reduce: 16 threads (t&15) share a row
  {
    const float c1 = cst[0], c2 = cst[1];
    #pragma unroll
    for (int p = 0; p < 2; ++p) {
      float d1 = d1a[p], d2 = d2a[p];
      #pragma unroll
      for (int off = 8; off > 0; off >>= 1) {
        d1 += __shfl_xor(d1, off); d2 += __shfl_xor(d2, off);
      }
      if ((t & 15) == 0) {
        const long row = row0 + p * 16 + srow;
        s1[row] = d1 + c1; s2[row] = d2 + c2;
      }
    }
  }

  // epilogue: zf direct from accumulators.
  #pragma unroll
  for (int nf = 0; nf < 4; ++nf) {
    const int o = w * 64 + nf * 16 + (l & 15);
    const float bv = bias[o];
    #pragma unroll
    for (int mf = 0; mf < 2; ++mf) {
      const int region = (bi & 1) * 4 + mf * 2 + (g >> 1);
      const int jq = (g & 1) * 4;
      uint2 zv;
      zv.x = cvt_pk_bf16(acc[mf][nf][0] + bv, acc[mf][nf][1] + bv);
      zv.y = cvt_pk_bf16(acc[mf][nf][2] + bv, acc[mf][nf][3] + bv);
      *(uint2*)&zf[((size_t)(bi >> 1) * 8 + region) * 2048 + (size_t)o * 8 + jq] = zv;
    }
  }
}

// ---------------------------------------------------------------------------
// attn: flash attention over graph mask, bf16 MFMA PV.
// SINGLE CHANGE vs R12: p_lds double-buffered -> ONE __syncthreads per phase
// (16 barriers, was 32). Halves the vmcnt(0) prefetch drains.
// Correctness: buf[p&1] written at phase p is re-written only at phase p+2,
// after barrier p+1, by which point all phase-p reads have drained.
// grid = 512 (XCD-swizzled); block = 512 thr (8 waves); 64 i-rows/block.
// ---------------------------------------------------------------------------
__global__ __launch_bounds__(512, 4) void attn_kernel(
    const unsigned short* __restrict__ zf, const float* __restrict__ s1g,
    const float* __restrict__ s2g, const int* __restrict__ adj,
    float* __restrict__ out)
{
  __shared__ unsigned short p_lds[2][64][72];   // 18432 B, double-buffered
  __shared__ float s2s[1024];
  __shared__ float s1s[64];
  __shared__ float sum_lds[64];

  const int t = threadIdx.x;
  const int l = t & 63;
  const int w = t >> 6;

  // XCD-aware bijective swizzle: 512 wgs = 8 xcds * 64
  const int wg = blockIdx.x;
  const int sw = (wg & 7) * 64 + (wg >> 3);
  const int b = sw >> 4;
  const int i0 = (sw & 15) * 64;

  const int i_loc = t >> 3;            // 0..63
  const int jb = (t & 7) * 8;          // 0..56

  const size_t adj_base = (size_t)b * 1024 * 1024 + (size_t)(i0 + i_loc) * 1024 + jb;
  const size_t zf_batch = (size_t)b * 16 * 16384;
  const size_t zf_lane  = (size_t)(l >> 4) * 2048 + (size_t)(w * 32 + (l & 15)) * 8;

  if (t < 64) s1s[t] = s1g[b * 1024 + i0 + t];
  s2s[t] = s2g[b * 1024 + t];
  s2s[512 + t] = s2g[b * 1024 + 512 + t];

  floatx4 acc[4][2];
  #pragma unroll
  for (int mf = 0; mf < 4; ++mf) {
    acc[mf][0] = (floatx4)0.f;
    acc[mf][1] = (floatx4)0.f;
  }
  float sm = 0.f;

  int4 ac0 = *(const int4*)&adj[adj_base];
  int4 ac1 = *(const int4*)&adj[adj_base + 4];

  short8 vz[2][4];
  {
    const unsigned short* zp = zf + zf_batch + zf_lane;
    vz[0][0] = *(const short8*)(zp);
    vz[0][1] = *(const short8*)(zp + 128);
    vz[0][2] = *(const short8*)(zp + 8192);
    vz[0][3] = *(const short8*)(zp + 8320);
  }
  __syncthreads();   // s1s/s2s ready
  const float s1v = s1s[i_loc];

  for (int jt2 = 0; jt2 < 1024; jt2 += 128) {
    #pragma unroll
    for (int ph = 0; ph < 2; ++ph) {
      const int jt = jt2 + ph * 64;

      // ---- masked logits (8/thread), fixed max = 0 ----
      const float4 s2a = *(const float4*)&s2s[jt + jb];
      const float4 s2b = *(const float4*)&s2s[jt + jb + 4];
      float e[8] = {s2a.x, s2a.y, s2a.z, s2a.w, s2b.x, s2b.y, s2b.z, s2b.w};
      const int am[8] = {ac0.x, ac0.y, ac0.z, ac0.w, ac1.x, ac1.y, ac1.z, ac1.w};
      #pragma unroll
      for (int q = 0; q < 8; ++q) {
        float x = s1v + e[q];
        x = fmaxf(x, LRELU_ALPHA * x);       // leaky-relu (alpha < 1)
        e[q] = am[q] > 0 ? x : NEG_MASK_V;
      }

      // ---- prefetch next phase's adj + z fragments ----
      if (jt + 64 < 1024) {
        ac0 = *(const int4*)&adj[adj_base + jt + 64];
        ac1 = *(const int4*)&adj[adj_base + jt + 68];
        const unsigned short* zp =
            zf + zf_batch + (size_t)((jt >> 6) + 1) * 16384 + zf_lane;
        vz[ph ^ 1][0] = *(const short8*)(zp);
        vz[ph ^ 1][1] = *(const short8*)(zp + 128);
        vz[ph ^ 1][2] = *(const short8*)(zp + 8192);
        vz[ph ^ 1][3] = *(const short8*)(zp + 8320);
      }

      // ---- exp + partial sum + hw bf16 pack ----
      float p[8];
      #pragma unroll
      for (int q = 0; q < 8; ++q) { p[q] = __expf(e[q]); sm += p[q]; }
      uint4 pk;
      pk.x = cvt_pk_bf16(p[0], p[1]);
      pk.y = cvt_pk_bf16(p[2], p[3]);
      pk.z = cvt_pk_bf16(p[4], p[5]);
      pk.w = cvt_pk_bf16(p[6], p[7]);
      *(uint4*)&p_lds[ph][i_loc][jb] = pk;

      __syncthreads();                       // p ready (single barrier/phase)

      // ---- PV MFMA: 16 per wave per phase ----
      #pragma unroll
      for (int kk = 0; kk < 2; ++kk) {
        #pragma unroll
        for (int mf = 0; mf < 4; ++mf) {
          const short8 af =
              *(const short8*)&p_lds[ph][mf * 16 + (l & 15)][kk * 32 + (l >> 4) * 8];
          acc[mf][0] = __builtin_amdgcn_mfma_f32_16x16x32_bf16(
              af, vz[ph][kk * 2 + 0], acc[mf][0], 0, 0, 0);
          acc[mf][1] = __builtin_amdgcn_mfma_f32_16x16x32_bf16(
              af, vz[ph][kk * 2 + 1], acc[mf][1], 0, 0, 0);
        }
      }
    }
  }

  // ---- final row-sum reduce (8 threads/row, lane-adjacent) ----
  sm += __shfl_xor(sm, 1);
  sm += __shfl_xor(sm, 2);
  sm += __shfl_xor(sm, 4);
  if ((t & 7) == 0) sum_lds[i_loc] = sm;
  __syncthreads();

  const size_t obase = ((size_t)b * 1024 + i0) * 256 + w * 32;
  #pragma unroll
  for (int mf = 0; mf < 4; ++mf) {
    const int rbase = mf * 16 + ((l >> 4) << 2);
    #pragma unroll
    for (int rg = 0; rg < 4; ++rg) {
      const float inv = 1.0f / sum_lds[rbase + rg];
      #pragma unroll
      for (int nf = 0; nf < 2; ++nf) {
        float v = acc[mf][nf][rg] * inv;
        v = v > 0.f ? v : expm1f(v);
        out[obase + (size_t)(rbase + rg) * 256 + nf * 16 + (l & 15)] = v;
      }
    }
  }
}

// ---------------------------------------------------------------------------
extern "C" void kernel_launch(void* const* d_in, const int* in_sizes, int n_in,
                              void* d_out, int out_size, void* d_ws, size_t ws_size,
                              hipStream_t stream) {
  const float* h    = (const float*)d_in[0];   // [32,1024,256] f32
  const int*   adj  = (const int*)d_in[1];     // [32,1024,1024] i32
  const float* W    = (const float*)d_in[2];   // [256,256] f32
  const float* bias = (const float*)d_in[3];   // [256] f32
  const float* a    = (const float*)d_in[4];   // [512] f32
  float* out = (float*)d_out;                  // [32,1024,256] f32

  // workspace layout
  unsigned short* zf = (unsigned short*)d_ws;                       // 16 MB
  float* s1  = (float*)((char*)d_ws + 16777216);                    // 128 KB
  float* s2  = (float*)((char*)d_ws + 16908288);                    // 128 KB
  float* u1  = (float*)((char*)d_ws + 17039360);                    // 1 KB
  float* u2  = (float*)((char*)d_ws + 17040384);                    // 1 KB
  float* cst = (float*)((char*)d_ws + 17041408);                    // 8 B
  unsigned short* Wf = (unsigned short*)((char*)d_ws + 17825792);   // 128 KB

  prep_kernel<<<dim3(33), dim3(256), 0, stream>>>(W, bias, a, Wf, u1, u2, cst);
  zmfma_kernel<<<dim3(1024), dim3(256), 0, stream>>>(h, Wf, bias, u1, u2, cst, zf, s1, s2);
  attn_kernel<<<dim3(512), dim3(512), 0, stream>>>(zf, s1, s2, adj, out);
}